// Round 8
// baseline (503.266 us; speedup 1.0000x reference)
//
#include <hip/hip_runtime.h>
#include <cmath>

// B=64, T=256 -> 16384 independent problems; 31 rows x 32 cols LAP per problem.
// Solver replicates the reference's fp32 arithmetic BIT-EXACTLY (incl. BIG=1e6
// potential trajectories whose 0.0625-quantized reduced costs decide tie-breaks
// -- R7 proved a non-trajectory-exact solver flips assignments).
// R8: the two 32-lane half-problems are decoupled via a single-step state
// machine (pop / aug / advance), removing per-phase max(lo,hi) lockstep waste.
#define NPROB 16384
#define PROBS_PER_BLOCK 4   // 128 threads, one half-wave (32 lanes) per problem

template<int CTRL>
__device__ __forceinline__ float fmin_dpp(float x) {
  int s = __builtin_amdgcn_update_dpp(0, __float_as_int(x), CTRL, 0xF, 0xF, true);
  return fminf(x, __int_as_float(s));
}

// min across each 32-lane half; all sources stay inside the 32-lane half.
// xor16 step: v_permlane16_swap_b32 (gfx950 VALU) instead of ds_swizzle.
typedef int v2i_t __attribute__((ext_vector_type(2)));
__device__ __forceinline__ float halfmin32(float x) {
  x = fmin_dpp<0xB1>(x);    // quad_perm xor1
  x = fmin_dpp<0x4E>(x);    // quad_perm xor2
  x = fmin_dpp<0x141>(x);   // row_half_mirror -> 8-min
  x = fmin_dpp<0x140>(x);   // row_mirror      -> 16-min
#if __has_builtin(__builtin_amdgcn_permlane16_swap)
  v2i_t r = __builtin_amdgcn_permlane16_swap(__float_as_int(x), __float_as_int(x),
                                             false, false);
  return fminf(__int_as_float(r.x), __int_as_float(r.y));
#else
  int s = __builtin_amdgcn_ds_swizzle(__float_as_int(x), 0x401F); // xor16
  return fminf(x, __int_as_float(s));
#endif
}

__device__ __forceinline__ int bperm_i(int addr, int v) {
  return __builtin_amdgcn_ds_bpermute(addr, v);
}
__device__ __forceinline__ float bperm_f(int addr, float v) {
  return __int_as_float(__builtin_amdgcn_ds_bpermute(addr, __float_as_int(v)));
}

// first-index argmin lane within each 32-lane half, from a full-wave ballot.
// |0x80000000 guards ctz(0) (inactive half's word; result unused there).
__device__ __forceinline__ int half_ctz(unsigned long long bal, bool hiHalf) {
  const int jlo = __builtin_ctz((unsigned)bal | 0x80000000u);
  const int jhi = __builtin_ctz((unsigned)(bal >> 32) | 0x80000000u);
  return hiHalf ? jhi : jlo;
}

__global__ __launch_bounds__(128, 5) void matcher_kernel(
    const float* __restrict__ position,   // (BT, 32, 3)
    const float* __restrict__ velocity,   // (BT, 32, 3)
    const float* __restrict__ logits,     // (BT, 32, 5)
    const float* __restrict__ targets,    // (BT, 32, 18)
    float* __restrict__ out)              // C (BT,31,32) ++ pred_idx (BT,31) ++ tgt_idx (BT,31)
{
#pragma clang fp contract(off)
  // 4*992*4 = 15872 B of LDS -> 10 blocks/CU, 20 waves/CU.
  __shared__ float sCm[PROBS_PER_BLOCK][992];

  const int tid  = threadIdx.x;
  const int lane = tid & 63;
  const int rel  = lane & 31;      // column j-1 (0-based col); also row r=rel+1 for u storage
  const int hs   = lane & 32;      // 0 lower half, 32 upper half
  const int hs4  = hs * 4;
  const bool hiHalf = (hs != 0);
  const int relp1 = rel + 1;
  const int lp   = tid >> 5;       // local problem 0..3
  const int bt   = blockIdx.x * PROBS_PER_BLOCK + lp;

  const float* pos = position + (size_t)bt * 96;
  const float* vel = velocity + (size_t)bt * 96;
  const float* lg  = logits   + (size_t)bt * 160;
  const float* tg  = targets  + (size_t)bt * 576;

  // ---------- per-lane target fields (lane rel <-> target column rel) ----------
  const float* trow = tg + rel * 18;
  const float tp0 = trow[0],  tp1 = trow[1],  tp2 = trow[2];
  const float tv0 = trow[3],  tv1 = trow[4],  tv2 = trow[5];
  const float o0  = trow[14], o1  = trow[15], o2  = trow[16], o3 = trow[17];
  const float ssum = ((o0 + o1) + o2) + o3;
  const float mxo  = fmaxf(fmaxf(fmaxf(o0, o1), o2), o3);
  const int idx4 = (o0 == mxo) ? 0 : ((o1 == mxo) ? 1 : ((o2 == mxo) ? 2 : 3));
  const int cls5 = (ssum == 0.0f) ? 0 : (idx4 + 1);
  const int validc = (ssum > 0.0f && cls5 != 1) ? 1 : 0;

  // ---------- per-lane softmax stats for row rel+1 (rel<31) ----------
  float m_l = 0.0f, s_l = 1.0f;
  if (rel < 31) {
    const float* lr = lg + (rel + 1) * 5;
    const float l0 = lr[0], l1 = lr[1], l2 = lr[2], l3 = lr[3], l4 = lr[4];
    m_l = fmaxf(fmaxf(fmaxf(fmaxf(l0, l1), l2), l3), l4);
    const float e0 = expf(l0 - m_l), e1 = expf(l1 - m_l), e2 = expf(l2 - m_l),
                e3 = expf(l3 - m_l), e4 = expf(l4 - m_l);
    s_l = (((e0 + e1) + e2) + e3) + e4;
  }

  // ---------- cost matrix: C (global) and masked Cm (LDS) ----------
  float* outC  = out + (size_t)bt * 992;
  float* cmrow = &sCm[lp][0];
  for (int r = 0; r < 31; ++r) {
    const float m_r = __shfl(m_l, hs + r, 64);
    const float s_r = __shfl(s_l, hs + r, 64);
    const float lgl = lg[(r + 1) * 5 + cls5];
    const float psel = expf(lgl - m_r) / s_r;          // bit-identical softmax elem
    const float pr0 = pos[(r + 1) * 3 + 0], pr1 = pos[(r + 1) * 3 + 1], pr2 = pos[(r + 1) * 3 + 2];
    const float vr0 = vel[(r + 1) * 3 + 0], vr1 = vel[(r + 1) * 3 + 1], vr2 = vel[(r + 1) * 3 + 2];
    const float cp = (fabsf(pr0 - tp0) + fabsf(pr1 - tp1)) + fabsf(pr2 - tp2);
    const float cv = (fabsf(vr0 - tv0) + fabsf(vr1 - tv1)) + fabsf(vr2 - tv2);
    const float Cv = (-psel + 5.0f * cp) + 2.0f * cv;  // W_CLASS=1, W_POS=5, W_VEL=2
    outC[r * 32 + rel]  = Cv;
    cmrow[r * 32 + rel] = validc ? Cv : 1000000.0f;    // BIG
  }
  // cmrow written & read by the same half-wave -> in-order LDS, no barrier

  // ---------- Jonker-Volgenant LAP: bit-exact, fused state machine ----------
  // Per-half states, dispatched each iteration by half-uniform predicates:
  //   pj != 0            -> one Dijkstra pop
  //   pj == 0 && j0 >= 0 -> one augmenting step
  //   pj == 0 && j0 < 0  -> advance phase (i += 1) + init + peeled first pop
  // Each half executes exactly the R4 kernel's op sequence on its own data;
  // only the interleaving with the other half changes (no inter-half data
  // flow), so the fp trajectory per problem is bit-identical.
  // INF-pinning: popped col's mv = 1e18; deltas <= ~1e8 << ulp(1e18)/2, so
  // mv -= d keeps INF exactly INF (used lanes feed INF to the reduction).
  // uq[j] = u[p[j]] phase-start snapshot: only ever read at not-yet-used
  // cols, whose u[p[j]] receives no deltas before that read (tree-only adds).
  const float INF = 1e18f;
  float u = 0.0f;   // u[rel+1]
  float v = 0.0f;   // v[rel+1]
  int   p = 0;      // p[rel+1]: matched row (1-based) or 0

  // pre-biased base: cmb[r*32] == sCm[lp][(r-1)*32 + rel], valid for r >= 1
  const float* cmb = cmrow + rel - 32;

  float uq = 0.0f, u_i = 0.0f, rowf = 0.0f, mv = 0.0f, u0 = 0.0f;
  int   way = -1, j0 = -1, pj = 0, i = 0;
  bool  used = false, done = false;

  for (;;) {
    if (__all(done)) break;

    if (pj != 0) {
      // ---- one Dijkstra pop (identical arithmetic to the phase-locked loop) ----
      const bool pop = (rel == j0);
      used = used || pop;                       // mask s_or (scalar pipe)
      mv = pop ? INF : mv;                      // pin popped col at INF
      rowf = (relp1 == pj) ? 1.0f : rowf;       // its row enters the tree
      const float a2 = cmb[pj * 32];
      const float c2 = used ? INF : ((a2 - u0) - v);
      if (c2 < mv) { mv = c2; way = j0; }       // used: INF<INF false -> frozen
      const float mv2 = halfmin32(mv);          // used lanes contribute INF
      j0 = half_ctz(__ballot(mv == mv2), hiHalf);
      const float dv = used ? mv2 : 0.0f;
      u = fmaf(rowf, mv2, u);                   // tree rows += delta
      v -= dv;                                  // used cols  -= delta
      mv -= mv2;                                // INF - d == INF exactly
      pj = bperm_i(hs4 + 4 * j0, p);            // independent, same-address
      u0 = bperm_f(hs4 + 4 * j0, uq);           //   broadcasts
    } else if (!done) {
      if (j0 >= 0) {
        // ---- one augmenting step (j0 = current col on the path) ----
        const int w1 = __shfl(way, hs + j0, 64);             // pred col or -1
        const int pv = __shfl(p, hs + ((w1 < 0) ? 0 : w1), 64);
        if (rel == j0) p = (w1 < 0) ? i : pv;
        j0 = (w1 < 0) ? -1 : w1;                // -1 = path done
      } else {
        // ---- advance to next phase: init + peeled first iteration ----
        i += 1;
        if (i > 31) {
          done = true;
        } else {
          uq  = bperm_f(hs4 + 4 * p - 4, u);    // p==0 -> garbage lane, never read
          u_i = __shfl(u, hs + (i - 1), 64);
          used = false;
          rowf = (rel == i - 1) ? 1.0f : 0.0f;  // 1.0 for rows in the tree
          way  = -1;                            // 0-based pred col, -1 = root
          mv = (cmb[i * 32] - u_i) - v;         // minv over fresh columns
          const float mval = halfmin32(mv);
          j0 = half_ctz(__ballot(mv == mval), hiHalf);   // first-index argmin
          u = fmaf(rowf, mval, u);              // u[i] += delta (others +0, exact)
          mv -= mval;
          pj = bperm_i(hs4 + 4 * j0, p);
          u0 = bperm_f(hs4 + 4 * j0, uq);       // u[p[j0]] (valid when pj!=0)
        }
      }
    }
  }

  // ---------- outputs: invert p -> row2col via ds_permute push ----------
  // dest lane (within half) = p-1; the one p==0 col pushes OOB (dropped).
  // Unpushed dest lanes (rel==31) read 0 -> consumed only under rel<31 mask.
  const int dsta = (p > 0) ? (hs4 + 4 * (p - 1)) : 0x7ffc;
  const int col  = __builtin_amdgcn_ds_permute(dsta, rel);
  const int colc = col & 31;
  const int av   = __shfl(validc, hs + colc, 64);
  if (rel < 31) {
    const size_t base1 = (size_t)NPROB * 992;
    const size_t base2 = base1 + (size_t)NPROB * 31;
    out[base1 + (size_t)bt * 31 + rel] = av ? (float)(rel + 1) : -1.0f;
    out[base2 + (size_t)bt * 31 + rel] = av ? (float)col : -1.0f;
  }
}

extern "C" void kernel_launch(void* const* d_in, const int* in_sizes, int n_in,
                              void* d_out, int out_size, void* d_ws, size_t ws_size,
                              hipStream_t stream) {
  const float* position = (const float*)d_in[0];
  const float* velocity = (const float*)d_in[1];
  const float* logits   = (const float*)d_in[2];
  const float* targets  = (const float*)d_in[3];
  float* out = (float*)d_out;
  matcher_kernel<<<NPROB / PROBS_PER_BLOCK, 128, 0, stream>>>(
      position, velocity, logits, targets, out);
}

// Round 9
// 377.756 us; speedup vs baseline: 1.3323x; 1.3323x over previous
//
#include <hip/hip_runtime.h>
#include <cmath>

// B=64, T=256 -> 16384 independent problems; 31 rows x 32 cols LAP per problem.
// Solver replicates the reference's fp32 arithmetic BIT-EXACTLY (incl. BIG=1e6
// potential trajectories whose 0.0625-quantized reduced costs decide tie-breaks
// -- R7 proved a non-trajectory-exact solver flips assignments).
// Session-best form (R4, 308.8 us): phase-locked halves, permlane16 halfmin,
// SALU used-mask, INF-pinned mv, snapshot-uq. R2/R6/R8 (stealing, reg-split
// occupancy, state-machine) all regressed; slot-shaves R5 neutral.
#define NPROB 16384
#define PROBS_PER_BLOCK 4   // 128 threads, one half-wave (32 lanes) per problem

template<int CTRL>
__device__ __forceinline__ float fmin_dpp(float x) {
  int s = __builtin_amdgcn_update_dpp(0, __float_as_int(x), CTRL, 0xF, 0xF, true);
  return fminf(x, __int_as_float(s));
}

// min across each 32-lane half; all sources stay inside the 32-lane half.
// xor16 step: v_permlane16_swap_b32 (gfx950 VALU) instead of ds_swizzle
// (LDS pipe). The swap exchanges a[16:31]<->b[0:15] and a[48:63]<->b[32:47];
// with a=b=x, fminf(a',b') = min(x[l], x[l^16]) within each 32-lane half.
typedef int v2i_t __attribute__((ext_vector_type(2)));
__device__ __forceinline__ float halfmin32(float x) {
  x = fmin_dpp<0xB1>(x);    // quad_perm xor1
  x = fmin_dpp<0x4E>(x);    // quad_perm xor2
  x = fmin_dpp<0x141>(x);   // row_half_mirror -> 8-min
  x = fmin_dpp<0x140>(x);   // row_mirror      -> 16-min
#if __has_builtin(__builtin_amdgcn_permlane16_swap)
  v2i_t r = __builtin_amdgcn_permlane16_swap(__float_as_int(x), __float_as_int(x),
                                             false, false);
  return fminf(__int_as_float(r.x), __int_as_float(r.y));
#else
  int s = __builtin_amdgcn_ds_swizzle(__float_as_int(x), 0x401F); // xor16
  return fminf(x, __int_as_float(s));
#endif
}

__device__ __forceinline__ int bperm_i(int addr, int v) {
  return __builtin_amdgcn_ds_bpermute(addr, v);
}
__device__ __forceinline__ float bperm_f(int addr, float v) {
  return __int_as_float(__builtin_amdgcn_ds_bpermute(addr, __float_as_int(v)));
}

__global__ __launch_bounds__(128, 5) void matcher_kernel(
    const float* __restrict__ position,   // (BT, 32, 3)
    const float* __restrict__ velocity,   // (BT, 32, 3)
    const float* __restrict__ logits,     // (BT, 32, 5)
    const float* __restrict__ targets,    // (BT, 32, 18)
    float* __restrict__ out)              // C (BT,31,32) ++ pred_idx (BT,31) ++ tgt_idx (BT,31)
{
#pragma clang fp contract(off)
  // 4*992*4 + 4*32*4 = 16384 B -> 10 blocks/CU, 20 waves/CU.
  __shared__ float sCm[PROBS_PER_BLOCK][992];
  __shared__ int   sR2c[PROBS_PER_BLOCK][32];

  const int tid  = threadIdx.x;
  const int lane = tid & 63;
  const int rel  = lane & 31;      // column j-1 (0-based col); also row r=rel+1 for u storage
  const int hs   = lane & 32;      // 0 lower half, 32 upper half
  const int hs4  = hs * 4;
  const int relp1 = rel + 1;
  const int lp   = tid >> 5;       // local problem 0..3
  const int bt   = blockIdx.x * PROBS_PER_BLOCK + lp;

  const float* pos = position + (size_t)bt * 96;
  const float* vel = velocity + (size_t)bt * 96;
  const float* lg  = logits   + (size_t)bt * 160;
  const float* tg  = targets  + (size_t)bt * 576;

  // ---------- per-lane target fields (lane rel <-> target column rel) ----------
  const float* trow = tg + rel * 18;
  const float tp0 = trow[0],  tp1 = trow[1],  tp2 = trow[2];
  const float tv0 = trow[3],  tv1 = trow[4],  tv2 = trow[5];
  const float o0  = trow[14], o1  = trow[15], o2  = trow[16], o3 = trow[17];
  const float ssum = ((o0 + o1) + o2) + o3;
  const float mxo  = fmaxf(fmaxf(fmaxf(o0, o1), o2), o3);
  const int idx4 = (o0 == mxo) ? 0 : ((o1 == mxo) ? 1 : ((o2 == mxo) ? 2 : 3));
  const int cls5 = (ssum == 0.0f) ? 0 : (idx4 + 1);
  const int validc = (ssum > 0.0f && cls5 != 1) ? 1 : 0;

  // ---------- per-lane softmax stats for row rel+1 (rel<31) ----------
  float m_l = 0.0f, s_l = 1.0f;
  if (rel < 31) {
    const float* lr = lg + (rel + 1) * 5;
    const float l0 = lr[0], l1 = lr[1], l2 = lr[2], l3 = lr[3], l4 = lr[4];
    m_l = fmaxf(fmaxf(fmaxf(fmaxf(l0, l1), l2), l3), l4);
    const float e0 = expf(l0 - m_l), e1 = expf(l1 - m_l), e2 = expf(l2 - m_l),
                e3 = expf(l3 - m_l), e4 = expf(l4 - m_l);
    s_l = (((e0 + e1) + e2) + e3) + e4;
  }

  // ---------- cost matrix: C (global) and masked Cm (LDS) ----------
  float* outC  = out + (size_t)bt * 992;
  float* cmrow = &sCm[lp][0];
  for (int r = 0; r < 31; ++r) {
    const float m_r = __shfl(m_l, hs + r, 64);
    const float s_r = __shfl(s_l, hs + r, 64);
    const float lgl = lg[(r + 1) * 5 + cls5];
    const float psel = expf(lgl - m_r) / s_r;          // bit-identical softmax elem
    const float pr0 = pos[(r + 1) * 3 + 0], pr1 = pos[(r + 1) * 3 + 1], pr2 = pos[(r + 1) * 3 + 2];
    const float vr0 = vel[(r + 1) * 3 + 0], vr1 = vel[(r + 1) * 3 + 1], vr2 = vel[(r + 1) * 3 + 2];
    const float cp = (fabsf(pr0 - tp0) + fabsf(pr1 - tp1)) + fabsf(pr2 - tp2);
    const float cv = (fabsf(vr0 - tv0) + fabsf(vr1 - tv1)) + fabsf(vr2 - tv2);
    const float Cv = (-psel + 5.0f * cp) + 2.0f * cv;  // W_CLASS=1, W_POS=5, W_VEL=2
    outC[r * 32 + rel]  = Cv;
    cmrow[r * 32 + rel] = validc ? Cv : 1000000.0f;    // BIG
  }
  // cmrow written & read by the same half-wave -> in-order LDS, no barrier

  // ---------- Jonker-Volgenant LAP: bit-exact, trimmed pop loop ----------
  // A popped ("used") column's mv is pinned to INF=1e18; deltas <= ~1e8 <<
  // ulp(1e18)/2 = 3.4e10, so "mv -= d" keeps INF exactly INF: used lanes
  // feed INF to the reduction with no extra select. `used` itself lives as
  // a lane-mask (v_cmp + scalar s_or), consumed by cndmasks.
  // NOTE: u0 = uq[j0] is only ever read at lanes still unused (argmin lane
  // is never used: used lanes hold exactly INF, mv2 is always finite), and
  // dv == 0 on unused lanes -> the reference's u[p[j]] maintenance adds 0
  // at every lane that is ever read. uq therefore stays the i-start
  // snapshot: bit-exact, no per-pop maintenance.
  const float INF = 1e18f;
  float u = 0.0f;   // u[rel+1]
  float v = 0.0f;   // v[rel+1]
  int   p = 0;      // p[rel+1]: matched row (1-based) or 0

  // pre-biased base: cmb[r*32] == sCm[lp][(r-1)*32 + rel], valid for r >= 1
  const float* cmb = cmrow + rel - 32;

  for (int i = 1; i <= 31; ++i) {
    // uq[j] = u[p[j]] snapshot (see note above; p==0 -> garbage lane, never read)
    const float uq = bperm_f(hs4 + 4 * p - 4, u);
    const float u_i = __shfl(u, hs + (i - 1), 64);

    bool  used = false;
    float rowf = (rel == i - 1) ? 1.0f : 0.0f;  // 1.0 for rows in the tree
    int   way  = -1;                             // 0-based pred col, -1 = root

    // --- peeled first iteration (tree = {row i}, all cols fresh) ---
    float mv = (cmb[i * 32] - u_i) - v;         // minv over fresh columns
    const float mval = halfmin32(mv);
    unsigned mh = (unsigned)(__ballot(mv == mval) >> hs);
    int j0 = (int)__builtin_ctz(mh);            // 0-based; first-index argmin
    u = fmaf(rowf, mval, u);                    // u[i] += delta (others +0, exact)
    mv -= mval;
    int   pj = bperm_i(hs4 + 4 * j0, p);
    float u0 = bperm_f(hs4 + 4 * j0, uq);       // u[p[j0]] (valid when pj!=0)

    // --- main Dijkstra loop (per-half divergent) ---
    while (pj != 0) {
      const bool pop = (rel == j0);
      used = used || pop;                       // mask s_or (scalar pipe)
      mv = pop ? INF : mv;                      // pin popped col at INF
      rowf = (relp1 == pj) ? 1.0f : rowf;       // its row enters the tree
      const float a2 = cmb[pj * 32];
      const float c2 = used ? INF : ((a2 - u0) - v);
      if (c2 < mv) { mv = c2; way = j0; }       // used: INF<INF false -> frozen
      const float mv2 = halfmin32(mv);          // used lanes contribute INF
      mh = (unsigned)(__ballot(mv == mv2) >> hs);
      j0 = (int)__builtin_ctz(mh);
      const float dv = used ? mv2 : 0.0f;
      u = fmaf(rowf, mv2, u);                   // tree rows += delta
      v -= dv;                                  // used cols  -= delta
      mv -= mv2;                                // INF - d == INF exactly
      pj = bperm_i(hs4 + 4 * j0, p);            // independent, same-address
      u0 = bperm_f(hs4 + 4 * j0, uq);           //   broadcasts
    }

    // --- augmenting path (j0 = free col, 0-based) ---
    while (true) {
      const int w1 = __shfl(way, hs + j0, 64);               // pred col or -1
      const int pv = __shfl(p, hs + ((w1 < 0) ? 0 : w1), 64);
      const int pja = (w1 < 0) ? i : pv;
      if (rel == j0) p = pja;
      if (w1 < 0) break;
      j0 = w1;
    }
  }

  // ---------- outputs: invert p -> row2col, then pred_idx / tgt_idx ----------
  if (p > 0) sR2c[lp][p - 1] = rel;          // rows 0..30 all covered
  const int col  = sR2c[lp][rel & 31];
  const int colc = col & 31;
  const int av   = __shfl(validc, hs + colc, 64);
  if (rel < 31) {
    const size_t base1 = (size_t)NPROB * 992;
    const size_t base2 = base1 + (size_t)NPROB * 31;
    out[base1 + (size_t)bt * 31 + rel] = av ? (float)(rel + 1) : -1.0f;
    out[base2 + (size_t)bt * 31 + rel] = av ? (float)col : -1.0f;
  }
}

extern "C" void kernel_launch(void* const* d_in, const int* in_sizes, int n_in,
                              void* d_out, int out_size, void* d_ws, size_t ws_size,
                              hipStream_t stream) {
  const float* position = (const float*)d_in[0];
  const float* velocity = (const float*)d_in[1];
  const float* logits   = (const float*)d_in[2];
  const float* targets  = (const float*)d_in[3];
  float* out = (float*)d_out;
  matcher_kernel<<<NPROB / PROBS_PER_BLOCK, 128, 0, stream>>>(
      position, velocity, logits, targets, out);
}